// Round 6
// baseline (235.463 us; speedup 1.0000x reference)
//
#include <hip/hip_runtime.h>

typedef _Float16 half8 __attribute__((ext_vector_type(8)));
typedef short short8 __attribute__((ext_vector_type(8)));
typedef float f32x4 __attribute__((ext_vector_type(4)));

#define NH 8

__device__ __forceinline__ unsigned short f2bf(float x) {
  union { float f; unsigned u; } v; v.f = x;
  unsigned r = v.u + 0x7FFFu + ((v.u >> 16) & 1u);
  return (unsigned short)(r >> 16);
}

// ---------------- K0a: q/k weights -> fragment-major [h][kc][k8][o][8] fp16 ----
// grid 256 = arr(2) x h(8) x ft(8) x os(2); 256 thr = 4 waves (o-groups) x 64 f-lanes
__global__ __launch_bounds__(256) void k0_qk(
    const float* __restrict__ wq, const float* __restrict__ wk,
    const float* __restrict__ omega,
    _Float16* __restrict__ wxq, _Float16* __restrict__ wxk) {
  const int bid = blockIdx.x;
  const int arr = bid >> 7;
  const int h = (bid >> 4) & 7;
  const int ft = (bid >> 1) & 7;
  const int os = bid & 1;
  const int f = threadIdx.x & 63;
  const int w = threadIdx.x >> 6;
  const float* wsrc = (arr ? wk : wq) + ((size_t)h * 512 + ft * 64 + f) * 64;
  float wreg[64];
#pragma unroll
  for (int i = 0; i < 16; ++i) {
    float4 v = *(const float4*)(wsrc + i * 4);
    wreg[i * 4] = v.x; wreg[i * 4 + 1] = v.y; wreg[i * 4 + 2] = v.z; wreg[i * 4 + 3] = v.w;
  }
  _Float16* outp = arr ? wxk : wxq;
  const int k8 = f >> 3, e = f & 7;
#pragma unroll 1
  for (int oo = 0; oo < 8; ++oo) {
    const int o = w * 16 + os * 8 + oo;
    const float* om = omega + o * 64;   // wave-uniform -> scalar loads
    float s = 0.f;
#pragma unroll
    for (int k = 0; k < 64; ++k) s = fmaf(wreg[k], om[k], s);
    outp[((((size_t)h * 8 + ft) * 8 + k8) * 64 + o) * 8 + e] = (_Float16)s;
  }
}

// ---------------- K0b: v weights -> fragment-major [h][kc][k8][o][8] fp16 ------
__global__ __launch_bounds__(256) void k0_v(
    const float* __restrict__ wv, _Float16* __restrict__ wvt) {
  int idx = blockIdx.x * 256 + threadIdx.x;  // 262144
  int h = idx >> 15, o = (idx >> 9) & 63, f = idx & 511;
  float val = wv[((size_t)h * 512 + f) * 64 + o];
  wvt[((((size_t)h * 8 + (f >> 6)) * 8 + ((f >> 3) & 7)) * 64 + o) * 8 + (f & 7)] = (_Float16)val;
}

// ---------------- fused_kv: proj(key)+phi, proj(value), kv-GEMM -> kvpart -------
// grid 1024 = h(8, top) x b(4) x sc(32); block 512 = 8 waves x 16 s-rows
// operand-swap: A = W (feat-major frags from LDS), B = x (direct global gather)
__global__ __launch_bounds__(512, 4) void fused_kv(
    const float* __restrict__ key, const float* __restrict__ value,
    const _Float16* __restrict__ wxk, const _Float16* __restrict__ wvt,
    float* __restrict__ kvpart) {
  __shared__ __align__(16) _Float16 W[4096];             // 8 KB, per-kc slice
  __shared__ __align__(16) unsigned short kpT[128][136]; // 34816 B
  __shared__ __align__(16) unsigned short vT[64][136];   // 17408 B
  const int bid = blockIdx.x;
  const int h = bid >> 7;
  const int r = bid & 127;
  const int b = r >> 5;
  const int sc = r & 31;
  const int tid = threadIdx.x;
  const int w = tid >> 6;
  const int lane = tid & 63;
  const int g = lane >> 4, c = lane & 15;
  const int bh = b * NH + h;
  const int cg = g * 8;
  const int scol = w * 16 + c;   // this lane's s-column within the 128-chunk

  const float* xk = key + (size_t)(b * 4096 + sc * 128 + scol) * 512;
  const float* xv = value + (size_t)(b * 4096 + sc * 128 + scol) * 512;
  const _Float16* wkb = wxk + (size_t)h * 32768;
  const _Float16* wvb = wvt + (size_t)h * 32768;

  short8 bones;
#pragma unroll
  for (int i = 0; i < 8; ++i) bones[i] = (c == 0) ? (short)0x3F80 : (short)0;

  f32x4 acc_kv[5];
#pragma unroll
  for (int j = 0; j < 5; ++j) acc_kv[j] = (f32x4){0.f, 0.f, 0.f, 0.f};

  // prologue prefetch: p=0 kc=0
  float4 xg0 = *(const float4*)(xk + cg);
  float4 xg1 = *(const float4*)(xk + cg + 4);
  float4 xg2 = *(const float4*)(xk + cg + 32);
  float4 xg3 = *(const float4*)(xk + cg + 36);
  half8 wr = *(const half8*)(wkb + tid * 8);

#pragma unroll 1
  for (int p = 0; p < 2; ++p) {
    f32x4 accp[4];
#pragma unroll
    for (int j = 0; j < 4; ++j) accp[j] = (f32x4){0.f, 0.f, 0.f, 0.f};

#pragma unroll 1
    for (int kc = 0; kc < 8; ++kc) {
      asm volatile("s_waitcnt lgkmcnt(0)" ::: "memory");
      __builtin_amdgcn_s_barrier();     // waves done reading W[kc-1]
      __builtin_amdgcn_sched_barrier(0);
      *(half8*)&W[tid * 8] = wr;
      asm volatile("s_waitcnt lgkmcnt(0)" ::: "memory");
      __builtin_amdgcn_s_barrier();     // W[kc] ready
      __builtin_amdgcn_sched_barrier(0);
      // build x B-fragments (vmcnt wait inserted by compiler)
      half8 xf0, xf1;
      xf0[0] = (_Float16)xg0.x; xf0[1] = (_Float16)xg0.y;
      xf0[2] = (_Float16)xg0.z; xf0[3] = (_Float16)xg0.w;
      xf0[4] = (_Float16)xg1.x; xf0[5] = (_Float16)xg1.y;
      xf0[6] = (_Float16)xg1.z; xf0[7] = (_Float16)xg1.w;
      xf1[0] = (_Float16)xg2.x; xf1[1] = (_Float16)xg2.y;
      xf1[2] = (_Float16)xg2.z; xf1[3] = (_Float16)xg2.w;
      xf1[4] = (_Float16)xg3.x; xf1[5] = (_Float16)xg3.y;
      xf1[6] = (_Float16)xg3.z; xf1[7] = (_Float16)xg3.w;
      // prefetch next tile (stays in flight across barriers)
      if (kc < 7) {
        const float* xb = (p ? xv : xk) + (kc + 1) * 64;
        xg0 = *(const float4*)(xb + cg);
        xg1 = *(const float4*)(xb + cg + 4);
        xg2 = *(const float4*)(xb + cg + 32);
        xg3 = *(const float4*)(xb + cg + 36);
        wr = *(const half8*)((p ? wvb : wkb) + (size_t)(kc + 1) * 4096 + tid * 8);
      } else if (p == 0) {
        xg0 = *(const float4*)(xv + cg);
        xg1 = *(const float4*)(xv + cg + 4);
        xg2 = *(const float4*)(xv + cg + 32);
        xg3 = *(const float4*)(xv + cg + 36);
        wr = *(const half8*)(wvb + tid * 8);
      }
      // W A-fragments + MFMA
#pragma unroll
      for (int mf = 0; mf < 4; ++mf) {
        half8 w0 = *(const half8*)&W[((0 + g) * 64 + mf * 16 + c) * 8];
        accp[mf] = __builtin_amdgcn_mfma_f32_16x16x32_f16(w0, xf0, accp[mf], 0, 0, 0);
      }
#pragma unroll
      for (int mf = 0; mf < 4; ++mf) {
        half8 w1 = *(const half8*)&W[((4 + g) * 64 + mf * 16 + c) * 8];
        accp[mf] = __builtin_amdgcn_mfma_f32_16x16x32_f16(w1, xf1, accp[mf], 0, 0, 0);
      }
    }

    if (p == 0) {  // key phase: phi -> kpT[feat][s]
      float ssl = 0.f;
#pragma unroll
      for (int mf = 0; mf < 4; ++mf)
#pragma unroll
        for (int j = 0; j < 4; ++j) ssl = fmaf(accp[mf][j], accp[mf][j], ssl);
      ssl += __shfl_xor(ssl, 16);
      ssl += __shfl_xor(ssl, 32);
      const float ss = ssl * 0.0078125f;  // ||xw||^2/128 == 0.5||k||^2
#pragma unroll
      for (int mf = 0; mf < 4; ++mf)
#pragma unroll
        for (int j = 0; j < 4; ++j) {
          const int feat = mf * 16 + g * 4 + j;
          const float v = accp[mf][j];
          kpT[feat][scol] = f2bf(__expf(v - ss) + 1e-9f);
          kpT[64 + feat][scol] = f2bf(__expf(-v - ss) + 1e-9f);
        }
    } else {  // value phase: vT[d][s], then kv-GEMM
#pragma unroll
      for (int mf = 0; mf < 4; ++mf)
#pragma unroll
        for (int j = 0; j < 4; ++j)
          vT[mf * 16 + g * 4 + j][scol] = f2bf(accp[mf][j]);
      asm volatile("s_waitcnt lgkmcnt(0)" ::: "memory");
      __builtin_amdgcn_s_barrier();
      __builtin_amdgcn_sched_barrier(0);
#pragma unroll
      for (int ks = 0; ks < 4; ++ks) {
        short8 a = *(const short8*)&kpT[w * 16 + c][ks * 32 + g * 8];
#pragma unroll
        for (int nf = 0; nf < 4; ++nf) {
          short8 bb = *(const short8*)&vT[nf * 16 + c][ks * 32 + g * 8];
          acc_kv[nf] = __builtin_amdgcn_mfma_f32_16x16x32_bf16(a, bb, acc_kv[nf], 0, 0, 0);
        }
        acc_kv[4] = __builtin_amdgcn_mfma_f32_16x16x32_bf16(a, bones, acc_kv[4], 0, 0, 0);
      }
    }
  }

  float* pbase = kvpart + ((size_t)sc * 32 + bh) * 10240;
#pragma unroll
  for (int nf = 0; nf < 5; ++nf)
#pragma unroll
    for (int j = 0; j < 4; ++j)
      pbase[(w * 16 + g * 4 + j) * 80 + nf * 16 + c] = acc_kv[nf][j];
}

// ---------------- K3b: reduce 32 partials -> kvnT fp16 [bh][80][128-perm], lsc --
__global__ __launch_bounds__(256) void k3b_reduce(
    const float* __restrict__ kvpart, _Float16* __restrict__ kvnt,
    float* __restrict__ lsc) {
  const int bh = blockIdx.x;
  const int by = blockIdx.y;
  const int tid = threadIdx.x;
  __shared__ float inv[128];
  const float* base = kvpart + (size_t)bh * 10240;
  const size_t stride = 327680;  // 32*10240
  if (tid < 128) {
    float s = 0.f;
#pragma unroll 8
    for (int kk = 0; kk < 32; ++kk) s += base[kk * stride + tid * 80 + 64];
    inv[tid] = 1.0f / s;
    if (by == 0) lsc[bh * 128 + tid] = __logf(s);
  }
  __syncthreads();
#pragma unroll
  for (int it = 0; it < 10; ++it) {
    int idx = it * 256 + tid;
    int d = by * 20 + (idx >> 7);
    int m = idx & 127;
    float s = 0.f;
#pragma unroll 8
    for (int kk = 0; kk < 32; ++kk) s += base[kk * stride + m * 80 + d];
    float val;
    if (d < 64) val = s * inv[m];
    else if (d == 64) val = 1.0f;
    else val = 0.f;
    int mst = ((m & 63) << 1) | (m >> 6);  // match qpT {pp,pm} packing
    kvnt[((size_t)bh * 80 + d) * 128 + mst] = (_Float16)val;
  }
}

// ---------------- fused_qo: proj(query)+phi -> qpT (LDS), out-GEMM -> out -------
// grid 1024 = h(8, top) x rt(128); block 512 = 8 waves x 16 t-rows
__global__ __launch_bounds__(512, 4) void fused_qo(
    const float* __restrict__ query, const _Float16* __restrict__ wxq,
    const _Float16* __restrict__ kvnt, const float* __restrict__ lsc,
    float* __restrict__ out) {
  __shared__ __align__(16) _Float16 W[4096];        // 8 KB
  __shared__ __align__(16) _Float16 qpT[128][136];  // 34816 B
  const int bid = blockIdx.x;
  const int h = bid >> 7;
  const int rt = bid & 127;
  const int b = rt >> 5;
  const int t0 = (rt & 31) * 128;
  const int bh = b * NH + h;
  const int tid = threadIdx.x;
  const int w = tid >> 6;
  const int lane = tid & 63;
  const int g = lane >> 4, c = lane & 15;
  const int cg = g * 8;

  const float* xq = query + (size_t)(rt * 128 + w * 16 + c) * 512;
  const _Float16* wb = wxq + (size_t)h * 32768;

  float4 xg0 = *(const float4*)(xq + cg);
  float4 xg1 = *(const float4*)(xq + cg + 4);
  float4 xg2 = *(const float4*)(xq + cg + 32);
  float4 xg3 = *(const float4*)(xq + cg + 36);
  half8 wr = *(const half8*)(wb + tid * 8);

  f32x4 accp[4];
#pragma unroll
  for (int j = 0; j < 4; ++j) accp[j] = (f32x4){0.f, 0.f, 0.f, 0.f};

#pragma unroll 1
  for (int kc = 0; kc < 8; ++kc) {
    asm volatile("s_waitcnt lgkmcnt(0)" ::: "memory");
    __builtin_amdgcn_s_barrier();
    __builtin_amdgcn_sched_barrier(0);
    *(half8*)&W[tid * 8] = wr;
    asm volatile("s_waitcnt lgkmcnt(0)" ::: "memory");
    __builtin_amdgcn_s_barrier();
    __builtin_amdgcn_sched_barrier(0);
    half8 xf0, xf1;
    xf0[0] = (_Float16)xg0.x; xf0[1] = (_Float16)xg0.y;
    xf0[2] = (_Float16)xg0.z; xf0[3] = (_Float16)xg0.w;
    xf0[4] = (_Float16)xg1.x; xf0[5] = (_Float16)xg1.y;
    xf0[6] = (_Float16)xg1.z; xf0[7] = (_Float16)xg1.w;
    xf1[0] = (_Float16)xg2.x; xf1[1] = (_Float16)xg2.y;
    xf1[2] = (_Float16)xg2.z; xf1[3] = (_Float16)xg2.w;
    xf1[4] = (_Float16)xg3.x; xf1[5] = (_Float16)xg3.y;
    xf1[6] = (_Float16)xg3.z; xf1[7] = (_Float16)xg3.w;
    if (kc < 7) {
      const float* xb = xq + (kc + 1) * 64;
      xg0 = *(const float4*)(xb + cg);
      xg1 = *(const float4*)(xb + cg + 4);
      xg2 = *(const float4*)(xb + cg + 32);
      xg3 = *(const float4*)(xb + cg + 36);
      wr = *(const half8*)(wb + (size_t)(kc + 1) * 4096 + tid * 8);
    }
#pragma unroll
    for (int mf = 0; mf < 4; ++mf) {
      half8 w0 = *(const half8*)&W[((0 + g) * 64 + mf * 16 + c) * 8];
      accp[mf] = __builtin_amdgcn_mfma_f32_16x16x32_f16(w0, xf0, accp[mf], 0, 0, 0);
    }
#pragma unroll
    for (int mf = 0; mf < 4; ++mf) {
      half8 w1 = *(const half8*)&W[((4 + g) * 64 + mf * 16 + c) * 8];
      accp[mf] = __builtin_amdgcn_mfma_f32_16x16x32_f16(w1, xf1, accp[mf], 0, 0, 0);
    }
  }

  // phi epilogue -> qpT[t][{pp,pm} interleaved feature]
  float Lp[4][4], Lm[4][4];
#pragma unroll
  for (int mf = 0; mf < 4; ++mf)
#pragma unroll
    for (int j = 0; j < 4; ++j) {
      const int feat = mf * 16 + g * 4 + j;
      Lp[mf][j] = lsc[bh * 128 + feat];
      Lm[mf][j] = lsc[bh * 128 + 64 + feat];
    }
  float ssl = 0.f;
#pragma unroll
  for (int mf = 0; mf < 4; ++mf)
#pragma unroll
    for (int j = 0; j < 4; ++j) ssl = fmaf(accp[mf][j], accp[mf][j], ssl);
  ssl += __shfl_xor(ssl, 16);
  ssl += __shfl_xor(ssl, 32);
  const float ss = ssl * 0.0078125f;
  float m0 = -1e30f;
#pragma unroll
  for (int mf = 0; mf < 4; ++mf)
#pragma unroll
    for (int j = 0; j < 4; ++j) {
      const float v = accp[mf][j];
      m0 = fmaxf(m0, fmaxf(v - ss + Lp[mf][j], -v - ss + Lm[mf][j]));
      m0 = fmaxf(m0, fmaxf(Lp[mf][j], Lm[mf][j]) - 20.723265f);  // eps floor
    }
  m0 = fmaxf(m0, __shfl_xor(m0, 16));
  m0 = fmaxf(m0, __shfl_xor(m0, 32));
  const float cm = m0;
#pragma unroll
  for (int mf = 0; mf < 4; ++mf)
#pragma unroll
    for (int j = 0; j < 4; ++j) {
      const int feat = mf * 16 + g * 4 + j;
      const float v = accp[mf][j];
      _Float16 pp = (_Float16)(__expf(v - ss + Lp[mf][j] - cm) +
                               1e-9f * __expf(Lp[mf][j] - cm));
      _Float16 pm = (_Float16)(__expf(-v - ss + Lm[mf][j] - cm) +
                               1e-9f * __expf(Lm[mf][j] - cm));
      union { unsigned u; _Float16 hh[2]; } pk;
      pk.hh[0] = pp; pk.hh[1] = pm;
      *(unsigned*)&qpT[w * 16 + c][2 * feat] = pk.u;
    }
  asm volatile("s_waitcnt lgkmcnt(0)" ::: "memory");
  __builtin_amdgcn_s_barrier();
  __builtin_amdgcn_sched_barrier(0);

  // out-GEMM: A = qpT rows (t), B = kvnt [d][feat]
  f32x4 acco[5];
#pragma unroll
  for (int j = 0; j < 5; ++j) acco[j] = (f32x4){0.f, 0.f, 0.f, 0.f};
  const _Float16* kvb = kvnt + (size_t)bh * 10240;
#pragma unroll
  for (int ks = 0; ks < 4; ++ks) {
    half8 a = *(const half8*)&qpT[w * 16 + c][ks * 32 + g * 8];
#pragma unroll
    for (int nf = 0; nf < 5; ++nf) {
      half8 bb = *(const half8*)(kvb + (size_t)(nf * 16 + c) * 128 + ks * 32 + g * 8);
      acco[nf] = __builtin_amdgcn_mfma_f32_16x16x32_f16(a, bb, acco[nf], 0, 0, 0);
    }
  }
  const int tb = t0 + w * 16 + g * 4;
#pragma unroll
  for (int j = 0; j < 4; ++j) {
    float nrm = __shfl(acco[4][j], (lane & 48));
    float invn = 1.0f / nrm;
#pragma unroll
    for (int nf = 0; nf < 4; ++nf) {
      out[((size_t)bh * 4096 + tb + j) * 64 + nf * 16 + c] = acco[nf][j] * invn;
    }
  }
}

extern "C" void kernel_launch(void* const* d_in, const int* in_sizes, int n_in,
                              void* d_out, int out_size, void* d_ws, size_t ws_size,
                              hipStream_t stream) {
  const float* query = (const float*)d_in[0];
  const float* value = (const float*)d_in[1];
  const float* key   = (const float*)d_in[2];
  const float* wq    = (const float*)d_in[3];
  const float* wv    = (const float*)d_in[4];
  const float* wk    = (const float*)d_in[5];
  const float* omega = (const float*)d_in[6];
  float* out = (float*)d_out;
  char* ws = (char*)d_ws;

  _Float16* wxq  = (_Float16*)(ws);                 // 524288
  _Float16* wxk  = (_Float16*)(ws + 524288);        // 524288
  _Float16* wvt  = (_Float16*)(ws + 1048576);       // 524288
  float* kvpart  = (float*)(ws + 1572864);          // 32*32*128*80*4 = 41943040
  _Float16* kvnt = (_Float16*)(ws + 43515904);      // 655360
  float* lsc     = (float*)(ws + 44171264);         // 16384

  k0_qk<<<256, 256, 0, stream>>>(wq, wk, omega, wxq, wxk);
  k0_v<<<1024, 256, 0, stream>>>(wv, wvt);
  fused_kv<<<1024, 512, 0, stream>>>(key, value, wxk, wvt, kvpart);
  k3b_reduce<<<dim3(32, 4), 256, 0, stream>>>(kvpart, kvnt, lsc);
  fused_qo<<<1024, 512, 0, stream>>>(query, wxq, kvnt, lsc, out);
}

// Round 7
// 113.359 us; speedup vs baseline: 2.0771x; 2.0771x over previous
//
#include <hip/hip_runtime.h>

typedef _Float16 half8 __attribute__((ext_vector_type(8)));
typedef _Float16 half4_t __attribute__((ext_vector_type(4)));
typedef short short8 __attribute__((ext_vector_type(8)));
typedef unsigned short u16x4 __attribute__((ext_vector_type(4)));
typedef float f32x4 __attribute__((ext_vector_type(4)));

#define NH 8

__device__ __forceinline__ unsigned short f2bf(float x) {
  union { float f; unsigned u; } v; v.f = x;
  unsigned r = v.u + 0x7FFFu + ((v.u >> 16) & 1u);
  return (unsigned short)(r >> 16);
}

// ---------------- K0a: q/k weights -> fragment-major [h][kc][k8][o][8] fp16 ----
__global__ __launch_bounds__(256) void k0_qk(
    const float* __restrict__ wq, const float* __restrict__ wk,
    const float* __restrict__ omega,
    _Float16* __restrict__ wxq, _Float16* __restrict__ wxk) {
  const int bid = blockIdx.x;
  const int arr = bid >> 7;
  const int h = (bid >> 4) & 7;
  const int ft = (bid >> 1) & 7;
  const int os = bid & 1;
  const int f = threadIdx.x & 63;
  const int w = threadIdx.x >> 6;
  const float* wsrc = (arr ? wk : wq) + ((size_t)h * 512 + ft * 64 + f) * 64;
  float wreg[64];
#pragma unroll
  for (int i = 0; i < 16; ++i) {
    float4 v = *(const float4*)(wsrc + i * 4);
    wreg[i * 4] = v.x; wreg[i * 4 + 1] = v.y; wreg[i * 4 + 2] = v.z; wreg[i * 4 + 3] = v.w;
  }
  _Float16* outp = arr ? wxk : wxq;
  const int k8 = f >> 3, e = f & 7;
#pragma unroll 1
  for (int oo = 0; oo < 8; ++oo) {
    const int o = w * 16 + os * 8 + oo;
    const float* om = omega + o * 64;   // wave-uniform -> scalar loads
    float s = 0.f;
#pragma unroll
    for (int k = 0; k < 64; ++k) s = fmaf(wreg[k], om[k], s);
    outp[((((size_t)h * 8 + ft) * 8 + k8) * 64 + o) * 8 + e] = (_Float16)s;
  }
}

// ---------------- K0b: v weights -> fragment-major [h][kc][k8][o][8] fp16 ------
__global__ __launch_bounds__(256) void k0_v(
    const float* __restrict__ wv, _Float16* __restrict__ wvt) {
  int idx = blockIdx.x * 256 + threadIdx.x;  // 262144
  int h = idx >> 15, o = (idx >> 9) & 63, f = idx & 511;
  float val = wv[((size_t)h * 512 + f) * 64 + o];
  wvt[((((size_t)h * 8 + (f >> 6)) * 8 + ((f >> 3) & 7)) * 64 + o) * 8 + (f & 7)] = (_Float16)val;
}

// ---------------- fused_kv: proj(key)+phi, proj(value), kv-GEMM -> kvpart ---------------
// grid 512 = h(8 top) x b(4) x sc(16); block 512 = 8 waves x 16 rows (r4 structure)
__global__ __launch_bounds__(512, 4) void fused_kv(
    const float* __restrict__ key, const float* __restrict__ value,
    const _Float16* __restrict__ wxk, const _Float16* __restrict__ wvt,
    float* __restrict__ kvpart) {
  __shared__ __align__(16) _Float16 A[128][72];        // 18432 B
  __shared__ __align__(16) _Float16 W[4096];           // 8192 B
  __shared__ __align__(16) unsigned short kpT[128][136]; // 34816 B
  __shared__ __align__(16) unsigned short vT[64][136];   // 17408 B
  const int bid = blockIdx.x;
  const int h = bid >> 6;
  const int b = (bid >> 4) & 3;
  const int sc = bid & 15;
  const int s0 = sc * 256;
  const int bh = b * NH + h;
  const int tid = threadIdx.x;
  const int w = tid >> 6;
  const int lane = tid & 63;
  const int g = lane >> 4, c = lane & 15;
  const int xr = lane >> 4;
  const int xc = (lane & 15) * 4;

  short8 bones;
#pragma unroll
  for (int i = 0; i < 8; ++i) bones[i] = (c == 0) ? (short)0x3F80 : (short)0;

  f32x4 acc_kv[5];
#pragma unroll
  for (int j = 0; j < 5; ++j) acc_kv[j] = (f32x4){0.f, 0.f, 0.f, 0.f};

  // prologue prefetch: p=0 (key, st=0), kc=0
  const float* xb0 = key + (size_t)(b * 4096 + s0 + w * 16 + xr) * 512 + xc;
  const _Float16* wb0 = wxk + (size_t)h * 32768;
  float4 xv[4];
  half8 wr;
#pragma unroll
  for (int i = 0; i < 4; ++i) xv[i] = *(const float4*)(xb0 + i * 2048);
  wr = *(const half8*)(wb0 + tid * 8);

#pragma unroll 1
  for (int p = 0; p < 4; ++p) {
    const float* xb = ((p & 1) ? value : key) +
                      (size_t)(b * 4096 + s0 + (p >> 1) * 128 + w * 16 + xr) * 512 + xc;
    const _Float16* wb = ((p & 1) ? wvt : wxk) + (size_t)h * 32768;

    f32x4 accp[4];
#pragma unroll
    for (int j = 0; j < 4; ++j) accp[j] = (f32x4){0.f, 0.f, 0.f, 0.f};

#pragma unroll 1
    for (int kc = 0; kc < 8; ++kc) {
      asm volatile("s_waitcnt lgkmcnt(0)" ::: "memory");
      __builtin_amdgcn_s_barrier();
      __builtin_amdgcn_sched_barrier(0);
#pragma unroll
      for (int i = 0; i < 4; ++i) {
        float vv[4] = {xv[i].x, xv[i].y, xv[i].z, xv[i].w};
        half4_t hv;
#pragma unroll
        for (int j2 = 0; j2 < 4; ++j2) hv[j2] = (_Float16)vv[j2];
        *(half4_t*)&A[w * 16 + i * 4 + xr][xc] = hv;
      }
      *(half8*)&W[tid * 8] = wr;
      if (kc < 7) {
#pragma unroll
        for (int i = 0; i < 4; ++i)
          xv[i] = *(const float4*)(xb + (kc + 1) * 64 + i * 2048);
        wr = *(const half8*)(wb + (kc + 1) * 4096 + tid * 8);
      } else if (p < 3) {
        const int pn = p + 1;
        const float* xb2 = ((pn & 1) ? value : key) +
                           (size_t)(b * 4096 + s0 + (pn >> 1) * 128 + w * 16 + xr) * 512 + xc;
        const _Float16* wb2 = ((pn & 1) ? wvt : wxk) + (size_t)h * 32768;
#pragma unroll
        for (int i = 0; i < 4; ++i) xv[i] = *(const float4*)(xb2 + i * 2048);
        wr = *(const half8*)(wb2 + tid * 8);
      }
      asm volatile("s_waitcnt lgkmcnt(0)" ::: "memory");
      __builtin_amdgcn_s_barrier();
      __builtin_amdgcn_sched_barrier(0);
#pragma unroll
      for (int ks = 0; ks < 2; ++ks) {
        half8 a = *(const half8*)&A[w * 16 + c][ks * 32 + g * 8];
#pragma unroll
        for (int nf = 0; nf < 4; ++nf) {
          half8 bf = *(const half8*)&W[((ks * 4 + g) * 64 + nf * 16 + c) * 8];
          accp[nf] = __builtin_amdgcn_mfma_f32_16x16x32_f16(a, bf, accp[nf], 0, 0, 0);
        }
      }
    }

    const int sl0 = w * 16 + g * 4;
    if ((p & 1) == 0) {  // key phase: phi -> kpT (bf16)
      float ss_[4];
#pragma unroll
      for (int j = 0; j < 4; ++j) {
        float s = 0.f;
#pragma unroll
        for (int nf = 0; nf < 4; ++nf) { float q = accp[nf][j]; s = fmaf(q, q, s); }
        s += __shfl_xor(s, 1); s += __shfl_xor(s, 2);
        s += __shfl_xor(s, 4); s += __shfl_xor(s, 8);
        ss_[j] = s * 0.0078125f;  // ||xw||^2/128 == 0.5||k||^2
      }
#pragma unroll
      for (int nf = 0; nf < 4; ++nf) {
        const int m = nf * 16 + c;
        u16x4 kp_p, kp_m;
#pragma unroll
        for (int j = 0; j < 4; ++j) {
          float v = accp[nf][j];
          kp_p[j] = f2bf(__expf(v - ss_[j]) + 1e-9f);
          kp_m[j] = f2bf(__expf(-v - ss_[j]) + 1e-9f);
        }
        *(u16x4*)&kpT[m][sl0] = kp_p;
        *(u16x4*)&kpT[64 + m][sl0] = kp_m;
      }
    } else {  // value phase: plain bf16 -> vT, then kv-GEMM
#pragma unroll
      for (int nf = 0; nf < 4; ++nf) {
        u16x4 vv;
#pragma unroll
        for (int j = 0; j < 4; ++j) vv[j] = f2bf(accp[nf][j]);
        *(u16x4*)&vT[nf * 16 + c][sl0] = vv;
      }
      asm volatile("s_waitcnt lgkmcnt(0)" ::: "memory");
      __builtin_amdgcn_s_barrier();
      __builtin_amdgcn_sched_barrier(0);
#pragma unroll
      for (int ks = 0; ks < 4; ++ks) {
        short8 a = *(const short8*)&kpT[w * 16 + c][ks * 32 + g * 8];
#pragma unroll
        for (int nf = 0; nf < 4; ++nf) {
          short8 bb = *(const short8*)&vT[nf * 16 + c][ks * 32 + g * 8];
          acc_kv[nf] = __builtin_amdgcn_mfma_f32_16x16x32_bf16(a, bb, acc_kv[nf], 0, 0, 0);
        }
        acc_kv[4] = __builtin_amdgcn_mfma_f32_16x16x32_bf16(a, bones, acc_kv[4], 0, 0, 0);
      }
      __builtin_amdgcn_s_barrier();
    }
  }

  float* pbase = kvpart + ((size_t)sc * 32 + bh) * 10240;
#pragma unroll
  for (int nf = 0; nf < 5; ++nf)
#pragma unroll
    for (int j = 0; j < 4; ++j) {
      int m = w * 16 + g * 4 + j;
      pbase[m * 80 + nf * 16 + c] = acc_kv[nf][j];
    }
}

// ---------------- k3a: denominator sums -> inv + lsc (tiny) ----------------
__global__ __launch_bounds__(128) void k3a_denom(
    const float* __restrict__ kvpart, float* __restrict__ invbuf,
    float* __restrict__ lsc) {
  const int bh = blockIdx.x;
  const int m = threadIdx.x;
  const float* base = kvpart + (size_t)bh * 10240 + m * 80 + 64;
  float s = 0.f;
#pragma unroll
  for (int kk = 0; kk < 16; ++kk) s += base[(size_t)kk * 327680];
  invbuf[bh * 128 + m] = 1.0f / s;
  lsc[bh * 128 + m] = __logf(s);
}

// ---------------- k3b: coalesced elementwise reduce + normalize ----------------
// grid (32 bh, 10); block 256; each thread reduces one float4 across 16 chunks
__global__ __launch_bounds__(256) void k3b_reduce(
    const float* __restrict__ kvpart, const float* __restrict__ invbuf,
    _Float16* __restrict__ kvnt) {
  const int bh = blockIdx.x;
  const int e0 = blockIdx.y * 1024 + threadIdx.x * 4;  // element in [0,10240)
  const int m = e0 / 80;
  const int d0 = e0 - m * 80;   // multiple of 4, all 4 elems share m
  const float* base = kvpart + (size_t)bh * 10240 + e0;
  f32x4 s = (f32x4){0.f, 0.f, 0.f, 0.f};
#pragma unroll
  for (int kk = 0; kk < 16; ++kk) {
    f32x4 v = *(const f32x4*)(base + (size_t)kk * 327680);
    s += v;
  }
  const float inv = invbuf[bh * 128 + m];
  const int mst = ((m & 63) << 1) | (m >> 6);  // match qpT {pp,pm} packing
  _Float16* outb = kvnt + (size_t)bh * 10240 + mst;
#pragma unroll
  for (int j = 0; j < 4; ++j) {
    const int d = d0 + j;
    float val;
    if (d < 64) val = s[j] * inv;
    else if (d == 64) val = 1.0f;
    else val = 0.f;
    outb[d * 128] = (_Float16)val;
  }
}

// ---------------- fused_qo: proj(query)+phi -> qpT (LDS), out-GEMM -> out ---------------
// grid 1024 = h(8 top) x rt(128); block 512 = 8 waves x 16 rows (r4 structure)
__global__ __launch_bounds__(512, 4) void fused_qo(
    const float* __restrict__ query, const _Float16* __restrict__ wxq,
    const _Float16* __restrict__ kvnt, const float* __restrict__ lsc,
    float* __restrict__ out) {
  __shared__ __align__(16) _Float16 A[128][72];     // 18432 B
  __shared__ __align__(16) _Float16 W[4096];        // 8192 B
  __shared__ __align__(16) _Float16 qpT[128][136];  // 34816 B
  const int bid = blockIdx.x;
  const int h = bid >> 7;
  const int rt = bid & 127;
  const int R0 = rt * 128;
  const int b = R0 >> 12;
  const int t0 = R0 & 4095;
  const int bh = b * NH + h;
  const int tid = threadIdx.x;
  const int w = tid >> 6;
  const int lane = tid & 63;
  const int g = lane >> 4, c = lane & 15;
  const int xr = lane >> 4;
  const int xc = (lane & 15) * 4;

  const float* xb = query + (size_t)(b * 4096 + t0 + w * 16 + xr) * 512 + xc;
  const _Float16* wb = wxq + (size_t)h * 32768;

  float4 xv[4];
  half8 wr;
#pragma unroll
  for (int i = 0; i < 4; ++i) xv[i] = *(const float4*)(xb + i * 2048);
  wr = *(const half8*)(wb + tid * 8);

  f32x4 accp[4];
#pragma unroll
  for (int j = 0; j < 4; ++j) accp[j] = (f32x4){0.f, 0.f, 0.f, 0.f};

#pragma unroll 1
  for (int kc = 0; kc < 8; ++kc) {
    asm volatile("s_waitcnt lgkmcnt(0)" ::: "memory");
    __builtin_amdgcn_s_barrier();
    __builtin_amdgcn_sched_barrier(0);
#pragma unroll
    for (int i = 0; i < 4; ++i) {
      float vv[4] = {xv[i].x, xv[i].y, xv[i].z, xv[i].w};
      half4_t hv;
#pragma unroll
      for (int j2 = 0; j2 < 4; ++j2) hv[j2] = (_Float16)vv[j2];
      *(half4_t*)&A[w * 16 + i * 4 + xr][xc] = hv;
    }
    *(half8*)&W[tid * 8] = wr;
    if (kc < 7) {
#pragma unroll
      for (int i = 0; i < 4; ++i)
        xv[i] = *(const float4*)(xb + (kc + 1) * 64 + i * 2048);
      wr = *(const half8*)(wb + (size_t)(kc + 1) * 4096 + tid * 8);
    }
    asm volatile("s_waitcnt lgkmcnt(0)" ::: "memory");
    __builtin_amdgcn_s_barrier();
    __builtin_amdgcn_sched_barrier(0);
#pragma unroll
    for (int ks = 0; ks < 2; ++ks) {
      half8 a = *(const half8*)&A[w * 16 + c][ks * 32 + g * 8];
#pragma unroll
      for (int nf = 0; nf < 4; ++nf) {
        half8 bf = *(const half8*)&W[((ks * 4 + g) * 64 + nf * 16 + c) * 8];
        accp[nf] = __builtin_amdgcn_mfma_f32_16x16x32_f16(a, bf, accp[nf], 0, 0, 0);
      }
    }
  }

  // phi epilogue -> qpT (fp16, {pp,pm} interleaved along feature)
  float Lp[4], Lm[4];
#pragma unroll
  for (int nf = 0; nf < 4; ++nf) {
    Lp[nf] = lsc[bh * 128 + nf * 16 + c];
    Lm[nf] = lsc[bh * 128 + 64 + nf * 16 + c];
  }
  float ss_[4], cm_[4];
#pragma unroll
  for (int j = 0; j < 4; ++j) {
    float s = 0.f;
#pragma unroll
    for (int nf = 0; nf < 4; ++nf) { float q = accp[nf][j]; s = fmaf(q, q, s); }
    s += __shfl_xor(s, 1); s += __shfl_xor(s, 2);
    s += __shfl_xor(s, 4); s += __shfl_xor(s, 8);
    ss_[j] = s * 0.0078125f;
  }
#pragma unroll
  for (int j = 0; j < 4; ++j) {
    float m0 = -1e30f;
#pragma unroll
    for (int nf = 0; nf < 4; ++nf) {
      float v = accp[nf][j];
      m0 = fmaxf(m0, fmaxf(v - ss_[j] + Lp[nf], -v - ss_[j] + Lm[nf]));
      m0 = fmaxf(m0, fmaxf(Lp[nf], Lm[nf]) - 20.723265f);  // eps floor
    }
    m0 = fmaxf(m0, __shfl_xor(m0, 1)); m0 = fmaxf(m0, __shfl_xor(m0, 2));
    m0 = fmaxf(m0, __shfl_xor(m0, 4)); m0 = fmaxf(m0, __shfl_xor(m0, 8));
    cm_[j] = m0;
  }
#pragma unroll
  for (int nf = 0; nf < 4; ++nf) {
    const int m = nf * 16 + c;
#pragma unroll
    for (int j = 0; j < 4; ++j) {
      float v = accp[nf][j];
      _Float16 pp = (_Float16)(__expf(v - ss_[j] + Lp[nf] - cm_[j]) +
                               1e-9f * __expf(Lp[nf] - cm_[j]));
      _Float16 pm = (_Float16)(__expf(-v - ss_[j] + Lm[nf] - cm_[j]) +
                               1e-9f * __expf(Lm[nf] - cm_[j]));
      union { unsigned u; _Float16 hh[2]; } pk;
      pk.hh[0] = pp; pk.hh[1] = pm;
      *(unsigned*)&qpT[w * 16 + g * 4 + j][2 * m] = pk.u;
    }
  }
  asm volatile("s_waitcnt lgkmcnt(0)" ::: "memory");
  __builtin_amdgcn_s_barrier();
  __builtin_amdgcn_sched_barrier(0);

  // out-GEMM
  f32x4 acco[5];
#pragma unroll
  for (int j = 0; j < 5; ++j) acco[j] = (f32x4){0.f, 0.f, 0.f, 0.f};
  const _Float16* kvb = kvnt + (size_t)bh * 10240;
#pragma unroll
  for (int ks = 0; ks < 4; ++ks) {
    half8 a = *(const half8*)&qpT[w * 16 + c][ks * 32 + g * 8];
#pragma unroll
    for (int nf = 0; nf < 5; ++nf) {
      half8 bb = *(const half8*)(kvb + (size_t)(nf * 16 + c) * 128 + ks * 32 + g * 8);
      acco[nf] = __builtin_amdgcn_mfma_f32_16x16x32_f16(a, bb, acco[nf], 0, 0, 0);
    }
  }
  const int tb = t0 + w * 16 + g * 4;
#pragma unroll
  for (int j = 0; j < 4; ++j) {
    float nrm = __shfl(acco[4][j], (lane & 48));
    float invn = 1.0f / nrm;
#pragma unroll
    for (int nf = 0; nf < 4; ++nf) {
      out[((size_t)bh * 4096 + tb + j) * 64 + nf * 16 + c] = acco[nf][j] * invn;
    }
  }
}

extern "C" void kernel_launch(void* const* d_in, const int* in_sizes, int n_in,
                              void* d_out, int out_size, void* d_ws, size_t ws_size,
                              hipStream_t stream) {
  const float* query = (const float*)d_in[0];
  const float* value = (const float*)d_in[1];
  const float* key   = (const float*)d_in[2];
  const float* wq    = (const float*)d_in[3];
  const float* wv    = (const float*)d_in[4];
  const float* wk    = (const float*)d_in[5];
  const float* omega = (const float*)d_in[6];
  float* out = (float*)d_out;
  char* ws = (char*)d_ws;

  _Float16* wxq  = (_Float16*)(ws);                 // 524288
  _Float16* wxk  = (_Float16*)(ws + 524288);        // 524288
  _Float16* wvt  = (_Float16*)(ws + 1048576);       // 524288
  float* kvpart  = (float*)(ws + 1572864);          // 16*32*10240*4 = 20971520
  _Float16* kvnt = (_Float16*)(ws + 22544384);      // 655360
  float* lsc     = (float*)(ws + 23199744);         // 16384
  float* invbuf  = (float*)(ws + 23216128);         // 16384

  k0_qk<<<256, 256, 0, stream>>>(wq, wk, omega, wxq, wxk);
  k0_v<<<1024, 256, 0, stream>>>(wv, wvt);
  fused_kv<<<512, 512, 0, stream>>>(key, value, wxk, wvt, kvpart);
  k3a_denom<<<32, 128, 0, stream>>>(kvpart, invbuf, lsc);
  k3b_reduce<<<dim3(32, 10), 256, 0, stream>>>(kvpart, invbuf, kvnt);
  fused_qo<<<1024, 512, 0, stream>>>(query, wxq, kvnt, lsc, out);
}